// Round 1
// baseline (59.044 us; speedup 1.0000x reference)
//
#include <hip/hip_runtime.h>

#define C_  20
#define H_  64
#define W_  2048
#define KA  5
#define KB  5
#define KN  24   // taps excluding center

#define TH  4
#define TW  64
#define TR  (TH + 4)   // 8
#define TC  (TW + 4)   // 68

// tap offset tables (row-major 5x5, center (2,2) removed)
__device__ __constant__ static const int d_dummy = 0; // keep file self-contained

__global__ __launch_bounds__(256) void lp_kernel(
    const float* __restrict__ data,
    const float* __restrict__ mask,
    const float* __restrict__ bilat,
    const float* __restrict__ ang_w,
    const float* __restrict__ bi_w,
    float* __restrict__ out)
{
    constexpr int KI[KN] = {0,0,0,0,0, 1,1,1,1,1, 2,2,2,2, 3,3,3,3,3, 4,4,4,4,4};
    constexpr int KJ[KN] = {0,1,2,3,4, 0,1,2,3,4, 0,1,3,4, 0,1,2,3,4, 0,1,2,3,4};

    __shared__ float s_data[C_][TR][TC];   // 43.5 KB
    __shared__ float s_mask[TR][TC];       // 2.2 KB

    const int tid = threadIdx.x;
    const int bid = blockIdx.x;
    const int ntx = W_ / TW;               // 32
    const int nty = H_ / TH;               // 16
    const int tx = bid % ntx;
    const int ty = (bid / ntx) % nty;
    const int b  = bid / (ntx * nty);

    const int y0 = ty * TH, x0 = tx * TW;

    // ---- stage data tile (all classes, halo 2, zero-padded) ----
    const float* dbase = data + (size_t)b * C_ * H_ * W_;
    for (int idx = tid; idx < C_ * TR * TC; idx += 256) {
        int cls = idx / (TR * TC);
        int rem = idx % (TR * TC);
        int r   = rem / TC;
        int col = rem % TC;
        int gy = y0 + r - 2, gx = x0 + col - 2;
        float v = 0.0f;
        if (gy >= 0 && gy < H_ && gx >= 0 && gx < W_)
            v = dbase[(size_t)cls * (H_ * W_) + gy * W_ + gx];
        s_data[cls][r][col] = v;
    }
    // ---- stage mask tile ----
    const float* mbase = mask + (size_t)b * H_ * W_;
    for (int idx = tid; idx < TR * TC; idx += 256) {
        int r = idx / TC, col = idx % TC;
        int gy = y0 + r - 2, gx = x0 + col - 2;
        float v = 0.0f;
        if (gy >= 0 && gy < H_ && gx >= 0 && gx < W_)
            v = mbase[gy * W_ + gx];
        s_mask[r][col] = v;
    }
    __syncthreads();

    // thread -> one output pixel
    const int lx  = tid % TW;     // lane within wave
    const int lyy = tid / TW;     // wave index = tile row
    const int y = y0 + lyy, x = x0 + lx;

    // bilateral for this pixel (coalesced global reads)
    float bb[KN];
    const float* bibase = bilat + (size_t)b * KN * (H_ * W_) + (size_t)y * W_ + x;
    #pragma unroll
    for (int kp = 0; kp < KN; ++kp)
        bb[kp] = bibase[(size_t)kp * (H_ * W_)];

    // mask at the 24 tap positions + center
    float mm[KN];
    #pragma unroll
    for (int k = 0; k < KN; ++k)
        mm[k] = s_mask[lyy + KI[k]][lx + KJ[k]];
    const float m_c = s_mask[lyy + 2][lx + 2];

    float bi_acc[C_];
    float biang[C_];
    #pragma unroll
    for (int c2 = 0; c2 < C_; ++c2) bi_acc[c2] = 0.0f;

    float* ang_out = out;
    float* bi_out  = out + (size_t)2 * C_ * (size_t)(H_ * W_);  // B*C*H*W = 2*20*64*2048

    #pragma unroll
    for (int cls = 0; cls < C_; ++cls) {
        float a_acc  = 0.0f;
        float ba_acc = 0.0f;
        #pragma unroll
        for (int k = 0; k < KN; ++k) {
            const int i = KI[k], j = KJ[k];
            const float v  = s_data[cls][lyy + i][lx + j];
            const float wa = ang_w[cls * 25 + i * 5 + j];  // wave-uniform -> s_load
            const float wb = bi_w [cls * 25 + i * 5 + j];
            a_acc  += wa * v;
            ba_acc += wb * v;
            // torch .view channel remap: flat = k*C + cls = c'*KN + k'
            const int flat = k * C_ + cls;
            bi_acc[flat / KN] += bb[flat % KN] * (v * mm[k]);
        }
        ang_out[((size_t)(b * C_ + cls) * H_ + y) * W_ + x] = a_acc;
        biang[cls] = ba_acc;
    }

    #pragma unroll
    for (int c2 = 0; c2 < C_; ++c2) {
        bi_out[((size_t)(b * C_ + c2) * H_ + y) * W_ + x] = m_c * biang[c2] * bi_acc[c2];
    }
}

extern "C" void kernel_launch(void* const* d_in, const int* in_sizes, int n_in,
                              void* d_out, int out_size, void* d_ws, size_t ws_size,
                              hipStream_t stream) {
    const float* data  = (const float*)d_in[0];
    const float* mask  = (const float*)d_in[1];
    const float* bilat = (const float*)d_in[2];
    const float* ang_w = (const float*)d_in[3];
    const float* bi_w  = (const float*)d_in[4];
    float* out = (float*)d_out;

    const int nblocks = 2 * (H_ / TH) * (W_ / TW);  // B * 16 * 32 = 1024
    lp_kernel<<<nblocks, 256, 0, stream>>>(data, mask, bilat, ang_w, bi_w, out);
}